// Round 4
// baseline (725.589 us; speedup 1.0000x reference)
//
#include <hip/hip_runtime.h>
#include <math.h>

typedef _Float16 f16_t;
typedef _Float16 f16x8 __attribute__((ext_vector_type(8)));
typedef _Float16 f16x4 __attribute__((ext_vector_type(4)));
typedef float f32x4 __attribute__((ext_vector_type(4)));

// fp32 -> fp16 weight conversion, row-major unchanged layout.
// W1p = ws[0..32768), W2p = ws[32768..98304)
__global__ void wconv(const float* __restrict__ W1, const float* __restrict__ W2,
                      f16_t* __restrict__ o) {
  int i = blockIdx.x * 256 + threadIdx.x;  // 0..65535
  if (i < 32768) o[i] = (f16_t)W1[i];
  o[32768 + i] = (f16_t)W2[i];
}

#define COMP(v, r) ((r) == 0 ? (v).x : (r) == 1 ? (v).y : (r) == 2 ? (v).z : (v).w)

// Transposed fused MLP: D[feat][edge] = W @ x^T.
// 1024 threads = 16 waves as 4 feat-rows (64 feats) x 4 edge-cols (32 edges); tile = 128 edges.
// xbuf [128 edges][256 feats] f16, XOR-swizzled in 16B groups: g' = (g&16) | ((g ^ edge) & 15).
// Weights stream global->VGPR (reg double-buffer, no barriers in GEMMs); x is LDS-stationary.
// LN stats alias dead regions of xbuf; static LDS = 64 KB exactly.
__global__ __launch_bounds__(1024, 4) void fused_mlp(
    const float* __restrict__ h,
    const int* __restrict__ src,
    const int* __restrict__ dst,
    const f16_t* __restrict__ wks,
    const float* __restrict__ b1, const float* __restrict__ g1, const float* __restrict__ be1,
    const float* __restrict__ b2, const float* __restrict__ g2, const float* __restrict__ be2,
    const float* __restrict__ w3, const float* __restrict__ b3,
    float* __restrict__ out, int E, int nrows) {
  __shared__ __attribute__((aligned(16))) f16_t xbuf[128 * 256];  // 64 KB
  float* ssum = (float*)xbuf;          // [512]  bytes [0,2048)    (aliases dead x rows)
  float* ssq = (float*)xbuf + 512;     // [512]  bytes [2048,4096)
  float* smean = (float*)xbuf + 1024;  // [128]  bytes [4096,4608)
  float* srstd = (float*)xbuf + 1152;  // [128]  bytes [4608,5120)

  const int t = threadIdx.x;
  const int ebase = blockIdx.x * 128;

  // ---------- gather: x0[edge][k] = h[src][k]*h[dst][k], fp16, swizzled ----------
  {
    const int m = t & 127;   // edge row
    const int j = t >> 7;    // 0..7 -> 16-float slice
    const int e = ebase + m;
    const int g0 = j * 2;
    f16_t* xrow = xbuf + m * 256;
    const int o0 = ((g0 ^ m) & 15) * 8;
    const int o1 = (((g0 + 1) ^ m) & 15) * 8;
    if (e < E) {
      int si = src[e], di = dst[e];
      si = ((unsigned)si < (unsigned)nrows) ? si : 0;
      di = ((unsigned)di < (unsigned)nrows) ? di : 0;
      const float* hs = h + (long long)si * 128 + j * 16;
      const float* hd = h + (long long)di * 128 + j * 16;
      const float4 a0 = *(const float4*)(hs);
      const float4 a1 = *(const float4*)(hs + 4);
      const float4 a2 = *(const float4*)(hs + 8);
      const float4 a3 = *(const float4*)(hs + 12);
      const float4 c0 = *(const float4*)(hd);
      const float4 c1 = *(const float4*)(hd + 4);
      const float4 c2 = *(const float4*)(hd + 8);
      const float4 c3 = *(const float4*)(hd + 12);
      f16x8 v0, v1;
      v0[0] = (f16_t)(a0.x * c0.x); v0[1] = (f16_t)(a0.y * c0.y);
      v0[2] = (f16_t)(a0.z * c0.z); v0[3] = (f16_t)(a0.w * c0.w);
      v0[4] = (f16_t)(a1.x * c1.x); v0[5] = (f16_t)(a1.y * c1.y);
      v0[6] = (f16_t)(a1.z * c1.z); v0[7] = (f16_t)(a1.w * c1.w);
      v1[0] = (f16_t)(a2.x * c2.x); v1[1] = (f16_t)(a2.y * c2.y);
      v1[2] = (f16_t)(a2.z * c2.z); v1[3] = (f16_t)(a2.w * c2.w);
      v1[4] = (f16_t)(a3.x * c3.x); v1[5] = (f16_t)(a3.y * c3.y);
      v1[6] = (f16_t)(a3.z * c3.z); v1[7] = (f16_t)(a3.w * c3.w);
      *(f16x8*)(xrow + o0) = v0;
      *(f16x8*)(xrow + o1) = v1;
    } else {
      f16x8 z = {};
      *(f16x8*)(xrow + o0) = z;
      *(f16x8*)(xrow + o1) = z;
    }
  }
  __syncthreads();  // (1) x0 ready

  const int lane = t & 63;
  const int wave = t >> 6;
  const int wf = wave >> 2;  // feat block (64 feats)
  const int we = wave & 3;   // edge block (32 edges)
  const int c = lane & 15;
  const int q = lane >> 4;
  const int featBase = wf * 64;
  const int e0 = we * 32 + c;  // edge for nse=0 (nse=1: +16)
  const int e1 = e0 + 16;

  // ---------- GEMM1: acc[feat][edge] += W1[feat][k] * x0[edge][k] ----------
  const f16_t* w1base = wks + (featBase + c) * 128 + q * 8;
  f32x4 acc[4][2];
#pragma unroll
  for (int msf = 0; msf < 4; ++msf)
#pragma unroll
    for (int nse = 0; nse < 2; ++nse) acc[msf][nse] = (f32x4){0.f, 0.f, 0.f, 0.f};

  {
    f16x8 af[2][4];
#pragma unroll
    for (int msf = 0; msf < 4; ++msf) af[0][msf] = *(const f16x8*)(w1base + msf * 2048);
#pragma unroll
    for (int kc = 0; kc < 4; ++kc) {
      if (kc < 3) {
#pragma unroll
        for (int msf = 0; msf < 4; ++msf)
          af[(kc + 1) & 1][msf] = *(const f16x8*)(w1base + msf * 2048 + (kc + 1) * 32);
      }
      const int gp = ((kc * 4 + q) ^ e0) & 15;
      f16x8 bf0 = *(const f16x8*)(xbuf + e0 * 256 + gp * 8);
      f16x8 bf1 = *(const f16x8*)(xbuf + e1 * 256 + gp * 8);
#pragma unroll
      for (int msf = 0; msf < 4; ++msf) {
        acc[msf][0] = __builtin_amdgcn_mfma_f32_16x16x32_f16(af[kc & 1][msf], bf0, acc[msf][0], 0, 0, 0);
        acc[msf][1] = __builtin_amdgcn_mfma_f32_16x16x32_f16(af[kc & 1][msf], bf1, acc[msf][1], 0, 0, 0);
      }
    }
  }
  __syncthreads();  // (2) all x0 reads done; xbuf reusable for stats

  // ---------- LN1 stats (in-lane over 16 feats, 2 shuffle steps over q) ----------
  {
    float s0 = 0.f, s1 = 0.f, q0 = 0.f, q1 = 0.f;
#pragma unroll
    for (int msf = 0; msf < 4; ++msf) {
      const float4 bv = *(const float4*)(b1 + featBase + msf * 16 + q * 4);
#pragma unroll
      for (int r = 0; r < 4; ++r) {
        const float b = COMP(bv, r);
        float v0 = acc[msf][0][r] + b, v1 = acc[msf][1][r] + b;
        acc[msf][0][r] = v0; acc[msf][1][r] = v1;
        s0 += v0; q0 += v0 * v0;
        s1 += v1; q1 += v1 * v1;
      }
    }
    s0 += __shfl_xor(s0, 16, 64); s0 += __shfl_xor(s0, 32, 64);
    q0 += __shfl_xor(q0, 16, 64); q0 += __shfl_xor(q0, 32, 64);
    s1 += __shfl_xor(s1, 16, 64); s1 += __shfl_xor(s1, 32, 64);
    q1 += __shfl_xor(q1, 16, 64); q1 += __shfl_xor(q1, 32, 64);
    if (q == 0) {
      ssum[wf * 128 + e0] = s0; ssq[wf * 128 + e0] = q0;
      ssum[wf * 128 + e1] = s1; ssq[wf * 128 + e1] = q1;
    }
  }
  __syncthreads();  // (3)
  if (t < 128) {
    float s = ssum[t] + ssum[128 + t] + ssum[256 + t] + ssum[384 + t];
    float sq = ssq[t] + ssq[128 + t] + ssq[256 + t] + ssq[384 + t];
    float mu = s * (1.f / 256.f);
    float var = sq * (1.f / 256.f) - mu * mu;
    smean[t] = mu;
    srstd[t] = rsqrtf(var + 1e-5f);
  }
  __syncthreads();  // (4)

  // ---------- LN1 normalize + ReLU -> x1 (read stats, barrier, then write) ----------
  {
    const float mu0 = smean[e0], rs0 = srstd[e0];
    const float mu1 = smean[e1], rs1 = srstd[e1];
    f16x4 hv[4][2];
#pragma unroll
    for (int msf = 0; msf < 4; ++msf) {
      const float4 gv = *(const float4*)(g1 + featBase + msf * 16 + q * 4);
      const float4 bev = *(const float4*)(be1 + featBase + msf * 16 + q * 4);
#pragma unroll
      for (int r = 0; r < 4; ++r) {
        const float gr = COMP(gv, r), ber = COMP(bev, r);
        hv[msf][0][r] = (f16_t)fmaxf((acc[msf][0][r] - mu0) * rs0 * gr + ber, 0.f);
        hv[msf][1][r] = (f16_t)fmaxf((acc[msf][1][r] - mu1) * rs1 * gr + ber, 0.f);
      }
    }
    __syncthreads();  // (5) smean/srstd consumed; xbuf fully writable
    const int j0 = (q & 1) * 4;
#pragma unroll
    for (int msf = 0; msf < 4; ++msf) {
      const int g = (featBase + msf * 16 + q * 4) >> 3;  // 0..31
      const int glo = g & 15, ghi = g & 16;
      *(f16x4*)(xbuf + e0 * 256 + (ghi | (glo ^ (e0 & 15))) * 8 + j0) = hv[msf][0];
      *(f16x4*)(xbuf + e1 * 256 + (ghi | (glo ^ (e1 & 15))) * 8 + j0) = hv[msf][1];
    }
  }
  __syncthreads();  // (6) x1 visible

  // ---------- GEMM2: acc2[feat][edge] += W2[feat][k] * x1[edge][k] ----------
  const f16_t* w2base = wks + 32768 + (featBase + c) * 256 + q * 8;
  f32x4 acc2[4][2];
#pragma unroll
  for (int msf = 0; msf < 4; ++msf)
#pragma unroll
    for (int nse = 0; nse < 2; ++nse) acc2[msf][nse] = (f32x4){0.f, 0.f, 0.f, 0.f};

  {
    f16x8 af[2][4];
#pragma unroll
    for (int msf = 0; msf < 4; ++msf) af[0][msf] = *(const f16x8*)(w2base + msf * 4096);
#pragma unroll
    for (int kc = 0; kc < 8; ++kc) {
      if (kc < 7) {
#pragma unroll
        for (int msf = 0; msf < 4; ++msf)
          af[(kc + 1) & 1][msf] = *(const f16x8*)(w2base + msf * 4096 + (kc + 1) * 32);
      }
      const int g = kc * 4 + q;  // 0..31
      const int gp = (g & 16) | ((g ^ e0) & 15);
      f16x8 bf0 = *(const f16x8*)(xbuf + e0 * 256 + gp * 8);
      f16x8 bf1 = *(const f16x8*)(xbuf + e1 * 256 + gp * 8);
#pragma unroll
      for (int msf = 0; msf < 4; ++msf) {
        acc2[msf][0] = __builtin_amdgcn_mfma_f32_16x16x32_f16(af[kc & 1][msf], bf0, acc2[msf][0], 0, 0, 0);
        acc2[msf][1] = __builtin_amdgcn_mfma_f32_16x16x32_f16(af[kc & 1][msf], bf1, acc2[msf][1], 0, 0, 0);
      }
    }
  }
  __syncthreads();  // (7) x1 reads done; stats regions writable

  // ---------- LN2 stats ----------
  {
    float s0 = 0.f, s1 = 0.f, q0 = 0.f, q1 = 0.f;
#pragma unroll
    for (int msf = 0; msf < 4; ++msf) {
      const float4 bv = *(const float4*)(b2 + featBase + msf * 16 + q * 4);
#pragma unroll
      for (int r = 0; r < 4; ++r) {
        const float b = COMP(bv, r);
        float v0 = acc2[msf][0][r] + b, v1 = acc2[msf][1][r] + b;
        acc2[msf][0][r] = v0; acc2[msf][1][r] = v1;
        s0 += v0; q0 += v0 * v0;
        s1 += v1; q1 += v1 * v1;
      }
    }
    s0 += __shfl_xor(s0, 16, 64); s0 += __shfl_xor(s0, 32, 64);
    q0 += __shfl_xor(q0, 16, 64); q0 += __shfl_xor(q0, 32, 64);
    s1 += __shfl_xor(s1, 16, 64); s1 += __shfl_xor(s1, 32, 64);
    q1 += __shfl_xor(q1, 16, 64); q1 += __shfl_xor(q1, 32, 64);
    if (q == 0) {
      ssum[wf * 128 + e0] = s0; ssq[wf * 128 + e0] = q0;
      ssum[wf * 128 + e1] = s1; ssq[wf * 128 + e1] = q1;
    }
  }
  __syncthreads();  // (8)
  if (t < 128) {
    float s = ssum[t] + ssum[128 + t] + ssum[256 + t] + ssum[384 + t];
    float sq = ssq[t] + ssq[128 + t] + ssq[256 + t] + ssq[384 + t];
    float mu = s * (1.f / 256.f);
    float var = sq * (1.f / 256.f) - mu * mu;
    smean[t] = mu;
    srstd[t] = rsqrtf(var + 1e-5f);
  }
  __syncthreads();  // (9)

  // ---------- LN2 normalize + ReLU + dot(W3) ----------
  {
    const float mu0 = smean[e0], rs0 = srstd[e0];
    const float mu1 = smean[e1], rs1 = srstd[e1];
    float p0 = 0.f, p1 = 0.f;
#pragma unroll
    for (int msf = 0; msf < 4; ++msf) {
      const float4 gv = *(const float4*)(g2 + featBase + msf * 16 + q * 4);
      const float4 bev = *(const float4*)(be2 + featBase + msf * 16 + q * 4);
      const float4 wv = *(const float4*)(w3 + featBase + msf * 16 + q * 4);
#pragma unroll
      for (int r = 0; r < 4; ++r) {
        const float gr = COMP(gv, r), ber = COMP(bev, r), wr = COMP(wv, r);
        float v0 = fmaxf((acc2[msf][0][r] - mu0) * rs0 * gr + ber, 0.f);
        float v1 = fmaxf((acc2[msf][1][r] - mu1) * rs1 * gr + ber, 0.f);
        p0 = fmaf(v0, wr, p0);
        p1 = fmaf(v1, wr, p1);
      }
    }
    p0 += __shfl_xor(p0, 16, 64); p0 += __shfl_xor(p0, 32, 64);
    p1 += __shfl_xor(p1, 16, 64); p1 += __shfl_xor(p1, 32, 64);
    if (q == 0) {
      ssum[wf * 128 + e0] = p0;  // [0,2048): disjoint from smean/srstd
      ssum[wf * 128 + e1] = p1;
    }
  }
  __syncthreads();  // (10)
  if (t < 128) {
    int e = ebase + t;
    if (e < E) {
      float sres = ssum[t] + ssum[128 + t] + ssum[256 + t] + ssum[384 + t] + b3[0];
      out[e] = 1.f / (1.f + __expf(-sres));
    }
  }
}

extern "C" void kernel_launch(void* const* d_in, const int* in_sizes, int n_in,
                              void* d_out, int out_size, void* d_ws, size_t ws_size,
                              hipStream_t stream) {
  const float* h = (const float*)d_in[0];
  const int* src = (const int*)d_in[1];
  const int* dst = (const int*)d_in[2];
  const float* W1 = (const float*)d_in[3];
  const float* b1 = (const float*)d_in[4];
  const float* g1 = (const float*)d_in[5];
  const float* be1 = (const float*)d_in[6];
  const float* W2 = (const float*)d_in[7];
  const float* b2 = (const float*)d_in[8];
  const float* g2 = (const float*)d_in[9];
  const float* be2 = (const float*)d_in[10];
  const float* W3 = (const float*)d_in[11];
  const float* b3 = (const float*)d_in[12];
  float* out = (float*)d_out;
  const int E = in_sizes[1];
  const int nrows = in_sizes[0] / 128;
  f16_t* wks = (f16_t*)d_ws;  // 98304 f16 = 196608 bytes

  wconv<<<256, 256, 0, stream>>>(W1, W2, wks);
  const int tiles = (E + 127) / 128;
  fused_mlp<<<tiles, 1024, 0, stream>>>(h, src, dst, wks, b1, g1, be1,
                                        b2, g2, be2, W3, b3, out, E, nrows);
}

// Round 5
// 525.482 us; speedup vs baseline: 1.3808x; 1.3808x over previous
//
#include <hip/hip_runtime.h>
#include <math.h>

typedef _Float16 f16_t;
typedef _Float16 f16x8 __attribute__((ext_vector_type(8)));
typedef _Float16 f16x4 __attribute__((ext_vector_type(4)));
typedef float f32x4 __attribute__((ext_vector_type(4)));

#define LDS_BYTES 141312

// fp32 -> fp16 weight conversion, row-major.
// W1p = ws[0..32768), W2p = ws[32768..98304)
__global__ void wconv(const float* __restrict__ W1, const float* __restrict__ W2,
                      f16_t* __restrict__ o) {
  int i = blockIdx.x * 256 + threadIdx.x;  // 0..65535
  if (i < 32768) o[i] = (f16_t)W1[i];
  o[32768 + i] = (f16_t)W2[i];
}

#define COMP(v, r) ((r) == 0 ? (v).x : (r) == 1 ? (v).y : (r) == 2 ? (v).z : (v).w)

// Transposed fused MLP: D[feat][edge] = W @ x^T. Tile = 256 edges.
// 1024 threads = 16 waves as 4 feat-rows (64 feats) x 4 edge-cols (64 edges).
// Weights stream global(L2)->VGPR inside the GEMM loops (no barriers there);
// x is LDS-stationary: x0 [256][128] f16 (64 KB, lower half), x1 [256][256] f16
// (128 KB, overwrites x0 after LN1). XOR swizzle in 16B groups keeps ds_read_b128 clean.
// amdgpu_waves_per_eu(4,4) pins the register budget at 128 VGPR/wave (4 waves/EU,
// 1 block/CU) so the prefetch/ILP registers survive the allocator. 7 barriers/block.
__global__ __launch_bounds__(1024) __attribute__((amdgpu_waves_per_eu(4, 4)))
void fused_mlp(
    const float* __restrict__ h,
    const int* __restrict__ src,
    const int* __restrict__ dst,
    const f16_t* __restrict__ wks,
    const float* __restrict__ b1, const float* __restrict__ g1, const float* __restrict__ be1,
    const float* __restrict__ b2, const float* __restrict__ g2, const float* __restrict__ be2,
    const float* __restrict__ w3, const float* __restrict__ b3,
    float* __restrict__ out, int E, int nrows) {
  extern __shared__ __attribute__((aligned(16))) char smem[];
  f16_t* xbuf = (f16_t*)smem;               // x0: [256][128]; later x1: [256][256]
  float* ssum = (float*)(smem + 131072);    // [1024] = [4 wf][256 e]
  float* ssq  = (float*)(smem + 135168);    // [1024]
  float* smean = (float*)(smem + 139264);   // [256]
  float* srstd = (float*)(smem + 140288);   // [256]

  const int t = threadIdx.x;
  const int ebase = blockIdx.x * 256;

  // ---------- gather: x0[e][k] = h[src][k]*h[dst][k], fp16, swizzled ----------
  {
    const int m = t >> 2;          // edge row 0..255
    const int kq = (t & 3) * 32;   // k-offset
    const int e = ebase + m;
    f16_t* xrow = xbuf + m * 128;
    if (e < E) {
      int si = src[e], di = dst[e];
      si = ((unsigned)si < (unsigned)nrows) ? si : 0;
      di = ((unsigned)di < (unsigned)nrows) ? di : 0;
      const float* hs = h + (long long)si * 128 + kq;
      const float* hd = h + (long long)di * 128 + kq;
#pragma unroll
      for (int i = 0; i < 4; ++i) {
        const float4 a0 = *(const float4*)(hs + i * 8);
        const float4 a1 = *(const float4*)(hs + i * 8 + 4);
        const float4 c0 = *(const float4*)(hd + i * 8);
        const float4 c1 = *(const float4*)(hd + i * 8 + 4);
        f16x8 v;
        v[0] = (f16_t)(a0.x * c0.x); v[1] = (f16_t)(a0.y * c0.y);
        v[2] = (f16_t)(a0.z * c0.z); v[3] = (f16_t)(a0.w * c0.w);
        v[4] = (f16_t)(a1.x * c1.x); v[5] = (f16_t)(a1.y * c1.y);
        v[6] = (f16_t)(a1.z * c1.z); v[7] = (f16_t)(a1.w * c1.w);
        const int g = (((kq >> 3) + i) ^ m) & 15;
        *(f16x8*)(xrow + g * 8) = v;
      }
    } else {
      f16x8 z = {};
#pragma unroll
      for (int i = 0; i < 4; ++i) {
        const int g = (((kq >> 3) + i) ^ m) & 15;
        *(f16x8*)(xrow + g * 8) = z;
      }
    }
  }
  __syncthreads();  // (1) x0 ready

  const int lane = t & 63;
  const int wave = t >> 6;
  const int wf = wave >> 2;  // feat-row 0..3 (64 feats)
  const int we = wave & 3;   // edge-col 0..3 (64 edges)
  const int c = lane & 15;
  const int q = lane >> 4;
  const int featBase = wf * 64;
  const int edgeBase = we * 64;

  // ---------- GEMM1: acc[feat][edge] += W1[feat][k] * x0[edge][k], K=128 ----------
  const f16_t* w1base = wks + (featBase + c) * 128 + q * 8;
  f32x4 acc[4][4];
#pragma unroll
  for (int msf = 0; msf < 4; ++msf)
#pragma unroll
    for (int n = 0; n < 4; ++n) acc[msf][n] = (f32x4){0.f, 0.f, 0.f, 0.f};

#pragma unroll
  for (int kc = 0; kc < 4; ++kc) {
    f16x8 af[4], bf[4];
#pragma unroll
    for (int msf = 0; msf < 4; ++msf)
      af[msf] = *(const f16x8*)(w1base + msf * 2048 + kc * 32);
    const int gp = ((kc * 4 + q) ^ c) & 15;
#pragma unroll
    for (int n = 0; n < 4; ++n)
      bf[n] = *(const f16x8*)(xbuf + (edgeBase + n * 16 + c) * 128 + gp * 8);
#pragma unroll
    for (int msf = 0; msf < 4; ++msf)
#pragma unroll
      for (int n = 0; n < 4; ++n)
        acc[msf][n] = __builtin_amdgcn_mfma_f32_16x16x32_f16(af[msf], bf[n], acc[msf][n], 0, 0, 0);
  }

  // ---------- LN1 stats (no barrier needed before: stats LDS disjoint from xbuf) ----------
  {
    float s[4] = {0.f, 0.f, 0.f, 0.f}, s2[4] = {0.f, 0.f, 0.f, 0.f};
#pragma unroll
    for (int msf = 0; msf < 4; ++msf) {
      const float4 bv = *(const float4*)(b1 + featBase + msf * 16 + q * 4);
#pragma unroll
      for (int r = 0; r < 4; ++r) {
        const float b = COMP(bv, r);
#pragma unroll
        for (int n = 0; n < 4; ++n) {
          float v = acc[msf][n][r] + b;
          acc[msf][n][r] = v;
          s[n] += v; s2[n] += v * v;
        }
      }
    }
#pragma unroll
    for (int n = 0; n < 4; ++n) {
      s[n] += __shfl_xor(s[n], 16, 64);  s[n] += __shfl_xor(s[n], 32, 64);
      s2[n] += __shfl_xor(s2[n], 16, 64); s2[n] += __shfl_xor(s2[n], 32, 64);
    }
    if (q == 0) {
#pragma unroll
      for (int n = 0; n < 4; ++n) {
        ssum[wf * 256 + edgeBase + n * 16 + c] = s[n];
        ssq[wf * 256 + edgeBase + n * 16 + c] = s2[n];
      }
    }
  }
  __syncthreads();  // (2) stats written; all waves past GEMM1 (x0 dead)
  if (t < 256) {
    float s = ssum[t] + ssum[256 + t] + ssum[512 + t] + ssum[768 + t];
    float sq = ssq[t] + ssq[256 + t] + ssq[512 + t] + ssq[768 + t];
    float mu = s * (1.f / 256.f);
    float var = sq * (1.f / 256.f) - mu * mu;
    smean[t] = mu;
    srstd[t] = rsqrtf(var + 1e-5f);
  }
  __syncthreads();  // (3) mean/rstd ready

  // ---------- LN1 normalize + ReLU -> x1 (stride-256 swizzled, overwrites x0) ----------
  {
    float mu[4], rs[4];
#pragma unroll
    for (int n = 0; n < 4; ++n) {
      mu[n] = smean[edgeBase + n * 16 + c];
      rs[n] = srstd[edgeBase + n * 16 + c];
    }
#pragma unroll
    for (int msf = 0; msf < 4; ++msf) {
      const float4 gv = *(const float4*)(g1 + featBase + msf * 16 + q * 4);
      const float4 bev = *(const float4*)(be1 + featBase + msf * 16 + q * 4);
      const int g = (featBase + msf * 16 + q * 4) >> 3;
      const int gp = (g & 16) | ((g ^ c) & 15);
      const int j0 = (q & 1) * 4;
#pragma unroll
      for (int n = 0; n < 4; ++n) {
        f16x4 hv;
#pragma unroll
        for (int r = 0; r < 4; ++r) {
          float v = (acc[msf][n][r] - mu[n]) * rs[n] * COMP(gv, r) + COMP(bev, r);
          hv[r] = (f16_t)fmaxf(v, 0.f);
        }
        *(f16x4*)(xbuf + (edgeBase + n * 16 + c) * 256 + gp * 8 + j0) = hv;
      }
    }
  }
  __syncthreads();  // (4) x1 visible

  // ---------- GEMM2: acc2[feat][edge] += W2[feat][k] * x1[edge][k], K=256 ----------
  const f16_t* w2base = wks + 32768 + (featBase + c) * 256 + q * 8;
  f32x4 acc2[4][4];
#pragma unroll
  for (int msf = 0; msf < 4; ++msf)
#pragma unroll
    for (int n = 0; n < 4; ++n) acc2[msf][n] = (f32x4){0.f, 0.f, 0.f, 0.f};

#pragma unroll
  for (int kc = 0; kc < 8; ++kc) {
    f16x8 af[4], bf[4];
#pragma unroll
    for (int msf = 0; msf < 4; ++msf)
      af[msf] = *(const f16x8*)(w2base + msf * 4096 + kc * 32);
    const int g = kc * 4 + q;  // 0..31
    const int gp = (g & 16) | ((g ^ c) & 15);
#pragma unroll
    for (int n = 0; n < 4; ++n)
      bf[n] = *(const f16x8*)(xbuf + (edgeBase + n * 16 + c) * 256 + gp * 8);
#pragma unroll
    for (int msf = 0; msf < 4; ++msf)
#pragma unroll
      for (int n = 0; n < 4; ++n)
        acc2[msf][n] = __builtin_amdgcn_mfma_f32_16x16x32_f16(af[msf], bf[n], acc2[msf][n], 0, 0, 0);
  }

  // ---------- LN2 stats ----------
  {
    float s[4] = {0.f, 0.f, 0.f, 0.f}, s2[4] = {0.f, 0.f, 0.f, 0.f};
#pragma unroll
    for (int msf = 0; msf < 4; ++msf) {
      const float4 bv = *(const float4*)(b2 + featBase + msf * 16 + q * 4);
#pragma unroll
      for (int r = 0; r < 4; ++r) {
        const float b = COMP(bv, r);
#pragma unroll
        for (int n = 0; n < 4; ++n) {
          float v = acc2[msf][n][r] + b;
          acc2[msf][n][r] = v;
          s[n] += v; s2[n] += v * v;
        }
      }
    }
#pragma unroll
    for (int n = 0; n < 4; ++n) {
      s[n] += __shfl_xor(s[n], 16, 64);  s[n] += __shfl_xor(s[n], 32, 64);
      s2[n] += __shfl_xor(s2[n], 16, 64); s2[n] += __shfl_xor(s2[n], 32, 64);
    }
    if (q == 0) {
#pragma unroll
      for (int n = 0; n < 4; ++n) {
        ssum[wf * 256 + edgeBase + n * 16 + c] = s[n];
        ssq[wf * 256 + edgeBase + n * 16 + c] = s2[n];
      }
    }
  }
  __syncthreads();  // (5)
  if (t < 256) {
    float s = ssum[t] + ssum[256 + t] + ssum[512 + t] + ssum[768 + t];
    float sq = ssq[t] + ssq[256 + t] + ssq[512 + t] + ssq[768 + t];
    float mu = s * (1.f / 256.f);
    float var = sq * (1.f / 256.f) - mu * mu;
    smean[t] = mu;
    srstd[t] = rsqrtf(var + 1e-5f);
  }
  __syncthreads();  // (6)

  // ---------- LN2 normalize + ReLU + dot(W3) + sigmoid ----------
  {
    float mu[4], rs[4], p[4] = {0.f, 0.f, 0.f, 0.f};
#pragma unroll
    for (int n = 0; n < 4; ++n) {
      mu[n] = smean[edgeBase + n * 16 + c];
      rs[n] = srstd[edgeBase + n * 16 + c];
    }
#pragma unroll
    for (int msf = 0; msf < 4; ++msf) {
      const float4 gv = *(const float4*)(g2 + featBase + msf * 16 + q * 4);
      const float4 bev = *(const float4*)(be2 + featBase + msf * 16 + q * 4);
      const float4 wv = *(const float4*)(w3 + featBase + msf * 16 + q * 4);
#pragma unroll
      for (int r = 0; r < 4; ++r) {
        const float gr = COMP(gv, r), ber = COMP(bev, r), wr = COMP(wv, r);
#pragma unroll
        for (int n = 0; n < 4; ++n) {
          float v = fmaxf((acc2[msf][n][r] - mu[n]) * rs[n] * gr + ber, 0.f);
          p[n] = fmaf(v, wr, p[n]);
        }
      }
    }
#pragma unroll
    for (int n = 0; n < 4; ++n) {
      p[n] += __shfl_xor(p[n], 16, 64);
      p[n] += __shfl_xor(p[n], 32, 64);
    }
    if (q == 0) {
#pragma unroll
      for (int n = 0; n < 4; ++n) ssum[wf * 256 + edgeBase + n * 16 + c] = p[n];
    }
  }
  __syncthreads();  // (7)
  if (t < 256) {
    int e = ebase + t;
    if (e < E) {
      float sres = ssum[t] + ssum[256 + t] + ssum[512 + t] + ssum[768 + t] + b3[0];
      out[e] = 1.f / (1.f + __expf(-sres));
    }
  }
}

extern "C" void kernel_launch(void* const* d_in, const int* in_sizes, int n_in,
                              void* d_out, int out_size, void* d_ws, size_t ws_size,
                              hipStream_t stream) {
  const float* h = (const float*)d_in[0];
  const int* src = (const int*)d_in[1];
  const int* dst = (const int*)d_in[2];
  const float* W1 = (const float*)d_in[3];
  const float* b1 = (const float*)d_in[4];
  const float* g1 = (const float*)d_in[5];
  const float* be1 = (const float*)d_in[6];
  const float* W2 = (const float*)d_in[7];
  const float* b2 = (const float*)d_in[8];
  const float* g2 = (const float*)d_in[9];
  const float* be2 = (const float*)d_in[10];
  const float* W3 = (const float*)d_in[11];
  const float* b3 = (const float*)d_in[12];
  float* out = (float*)d_out;
  const int E = in_sizes[1];
  const int nrows = in_sizes[0] / 128;
  f16_t* wks = (f16_t*)d_ws;  // 98304 f16 = 196608 bytes

  wconv<<<256, 256, 0, stream>>>(W1, W2, wks);
  hipFuncSetAttribute((const void*)fused_mlp,
                      hipFuncAttributeMaxDynamicSharedMemorySize, LDS_BYTES);
  const int tiles = (E + 255) / 256;
  fused_mlp<<<tiles, 1024, LDS_BYTES, stream>>>(h, src, dst, wks, b1, g1, be1,
                                                b2, g2, be2, W3, b3, out, E, nrows);
}

// Round 6
// 324.395 us; speedup vs baseline: 2.2367x; 1.6199x over previous
//
#include <hip/hip_runtime.h>
#include <math.h>

typedef _Float16 f16_t;
typedef _Float16 f16x8 __attribute__((ext_vector_type(8)));
typedef _Float16 f16x4 __attribute__((ext_vector_type(4)));
typedef float f32x4 __attribute__((ext_vector_type(4)));

#define LDS_BYTES 136192

// fp32 -> fp16 weights into d_ws with XOR-16B-group swizzle baked in.
// W1: [256 n][128 k] -> o[n*128 + (((k>>3)^n)&15)*8 + (k&7)], at offset 0.
// W2: split into k-halves [half][256 n][128 kk], same intra-row swizzle, at 32768.
__global__ void wconv(const float* __restrict__ W1, const float* __restrict__ W2,
                      f16_t* __restrict__ o) {
  int i = blockIdx.x * 256 + threadIdx.x;  // 0..65535
  if (i < 32768) {
    int n = i >> 7, k = i & 127;
    o[n * 128 + ((((k >> 3) ^ n) & 15) * 8) + (k & 7)] = (f16_t)W1[i];
  }
  {
    int n = i >> 8, k = i & 255;
    int half = k >> 7, kk = k & 127;
    o[32768 + half * 32768 + n * 128 + ((((kk >> 3) ^ n) & 15) * 8) + (kk & 7)] =
        (f16_t)W2[i];
  }
}

__device__ __forceinline__ void stage16(const f16_t* g, f16_t* l) {
  __builtin_amdgcn_global_load_lds(
      (const __attribute__((address_space(1))) void*)g,
      (__attribute__((address_space(3))) void*)l, 16, 0, 0);
}

#define COMP(v, r) ((r) == 0 ? (v).x : (r) == 1 ? (v).y : (r) == 2 ? (v).z : (v).w)

// Transposed fused MLP: D[feat][edge] = W @ x^T. Tile = 128 edges, 1024 threads,
// 16 waves as 4 feat-rows (64 feats) x 4 edge-cols (32 edges). acc[4][2]=32 regs
// (the no-spill footprint proven in r3; this toolchain pins 1024-thr kernels at 64 regs).
// Weights deduped via LDS but staged in whole phases (W1 64KB, W2 in two 64KB k-halves):
// ZERO barriers inside the GEMM loops, 9 barriers/block total.
// LDS: wlds 64KB | xlds 64KB (x0 stride-128, then x1 stride-256 overwrites) | stats 5KB.
__global__ __launch_bounds__(1024) void fused_mlp(
    const float* __restrict__ h,
    const int* __restrict__ src,
    const int* __restrict__ dst,
    const f16_t* __restrict__ wks,
    const float* __restrict__ b1, const float* __restrict__ g1, const float* __restrict__ be1,
    const float* __restrict__ b2, const float* __restrict__ g2, const float* __restrict__ be2,
    const float* __restrict__ w3, const float* __restrict__ b3,
    float* __restrict__ out, int E, int nrows) {
  extern __shared__ __attribute__((aligned(16))) char smem[];
  f16_t* wlds = (f16_t*)smem;               // 64 KB: W1, then W2 half0, then half1
  f16_t* xlds = (f16_t*)(smem + 65536);     // 64 KB: x0 [128][128], then x1 [128][256]
  float* ssum = (float*)(smem + 131072);    // [4][128]
  float* ssq  = (float*)(smem + 133120);    // [4][128]
  float* smean = (float*)(smem + 135168);   // [128]
  float* srstd = (float*)(smem + 135680);   // [128]

  const int t = threadIdx.x;
  const int ebase = blockIdx.x * 128;

  auto stage64k = [&](int srcOff) {  // 64 KB wks -> wlds, lane-linear
#pragma unroll
    for (int p = 0; p < 4; ++p)
      stage16(wks + srcOff + p * 8192 + t * 8, wlds + p * 8192 + t * 8);
  };

  // W1 in flight while we gather
  stage64k(0);

  // ---------- gather: x0[m][k] = h[src][k]*h[dst][k], fp16, swizzled stride-128 ----------
  {
    const int m = t >> 3;         // edge row 0..127
    const int j = t & 7;          // 16-float slice
    const int e = ebase + m;
    f16_t* xrow = xlds + m * 128;
    const int g0 = ((j * 2) ^ m) & 15;
    const int g1i = ((j * 2 + 1) ^ m) & 15;
    if (e < E) {
      int si = src[e], di = dst[e];
      si = ((unsigned)si < (unsigned)nrows) ? si : 0;
      di = ((unsigned)di < (unsigned)nrows) ? di : 0;
      const float* hs = h + (long long)si * 128 + j * 16;
      const float* hd = h + (long long)di * 128 + j * 16;
      const float4 a0 = *(const float4*)(hs);
      const float4 a1 = *(const float4*)(hs + 4);
      const float4 a2 = *(const float4*)(hs + 8);
      const float4 a3 = *(const float4*)(hs + 12);
      const float4 c0 = *(const float4*)(hd);
      const float4 c1 = *(const float4*)(hd + 4);
      const float4 c2 = *(const float4*)(hd + 8);
      const float4 c3 = *(const float4*)(hd + 12);
      f16x8 v0, v1;
      v0[0] = (f16_t)(a0.x * c0.x); v0[1] = (f16_t)(a0.y * c0.y);
      v0[2] = (f16_t)(a0.z * c0.z); v0[3] = (f16_t)(a0.w * c0.w);
      v0[4] = (f16_t)(a1.x * c1.x); v0[5] = (f16_t)(a1.y * c1.y);
      v0[6] = (f16_t)(a1.z * c1.z); v0[7] = (f16_t)(a1.w * c1.w);
      v1[0] = (f16_t)(a2.x * c2.x); v1[1] = (f16_t)(a2.y * c2.y);
      v1[2] = (f16_t)(a2.z * c2.z); v1[3] = (f16_t)(a2.w * c2.w);
      v1[4] = (f16_t)(a3.x * c3.x); v1[5] = (f16_t)(a3.y * c3.y);
      v1[6] = (f16_t)(a3.z * c3.z); v1[7] = (f16_t)(a3.w * c3.w);
      *(f16x8*)(xrow + g0 * 8) = v0;
      *(f16x8*)(xrow + g1i * 8) = v1;
    } else {
      f16x8 z = {};
      *(f16x8*)(xrow + g0 * 8) = z;
      *(f16x8*)(xrow + g1i * 8) = z;
    }
  }
  __syncthreads();  // (1) x0 + W1 ready

  const int lane = t & 63;
  const int wave = t >> 6;
  const int wf = wave >> 2;  // 0..3: 64 feats
  const int we = wave & 3;   // 0..3: 32 edges
  const int c = lane & 15;
  const int q = lane >> 4;
  const int featBase = wf * 64;
  const int edgeBase = we * 32;
  const int e0 = edgeBase + c, e1 = e0 + 16;

  // ---------- GEMM1: acc[feat][edge] += W1[feat][k]*x0[edge][k], K=128, no barriers ----------
  f32x4 acc[4][2];
#pragma unroll
  for (int msf = 0; msf < 4; ++msf)
#pragma unroll
    for (int n = 0; n < 2; ++n) acc[msf][n] = (f32x4){0.f, 0.f, 0.f, 0.f};

#pragma unroll
  for (int kc = 0; kc < 4; ++kc) {
    const int gp = ((kc * 4 + q) ^ c) & 15;
    f16x8 af[4], bf[2];
#pragma unroll
    for (int msf = 0; msf < 4; ++msf)
      af[msf] = *(const f16x8*)(wlds + (featBase + msf * 16 + c) * 128 + gp * 8);
    bf[0] = *(const f16x8*)(xlds + e0 * 128 + gp * 8);
    bf[1] = *(const f16x8*)(xlds + e1 * 128 + gp * 8);
#pragma unroll
    for (int msf = 0; msf < 4; ++msf)
#pragma unroll
      for (int n = 0; n < 2; ++n)
        acc[msf][n] = __builtin_amdgcn_mfma_f32_16x16x32_f16(af[msf], bf[n], acc[msf][n], 0, 0, 0);
  }

  // ---------- LN1 stats ----------
  {
    float s0 = 0.f, s1 = 0.f, q0 = 0.f, q1 = 0.f;
#pragma unroll
    for (int msf = 0; msf < 4; ++msf) {
      const float4 bv = *(const float4*)(b1 + featBase + msf * 16 + q * 4);
#pragma unroll
      for (int r = 0; r < 4; ++r) {
        const float b = COMP(bv, r);
        float v0 = acc[msf][0][r] + b, v1 = acc[msf][1][r] + b;
        acc[msf][0][r] = v0; acc[msf][1][r] = v1;
        s0 += v0; q0 += v0 * v0;
        s1 += v1; q1 += v1 * v1;
      }
    }
    s0 += __shfl_xor(s0, 16, 64); s0 += __shfl_xor(s0, 32, 64);
    q0 += __shfl_xor(q0, 16, 64); q0 += __shfl_xor(q0, 32, 64);
    s1 += __shfl_xor(s1, 16, 64); s1 += __shfl_xor(s1, 32, 64);
    q1 += __shfl_xor(q1, 16, 64); q1 += __shfl_xor(q1, 32, 64);
    if (q == 0) {
      ssum[wf * 128 + e0] = s0; ssq[wf * 128 + e0] = q0;
      ssum[wf * 128 + e1] = s1; ssq[wf * 128 + e1] = q1;
    }
  }
  __syncthreads();  // (2) GEMM1 done everywhere; stats written; wlds dead
  stage64k(32768);  // W2 half0 -> wlds (drains at next barrier)
  if (t < 128) {
    float s = ssum[t] + ssum[128 + t] + ssum[256 + t] + ssum[384 + t];
    float sq = ssq[t] + ssq[128 + t] + ssq[256 + t] + ssq[384 + t];
    float mu = s * (1.f / 256.f);
    float var = sq * (1.f / 256.f) - mu * mu;
    smean[t] = mu;
    srstd[t] = rsqrtf(var + 1e-5f);
  }
  __syncthreads();  // (3) mean/rstd ready; W2h0 drained

  // ---------- LN1 normalize + ReLU -> x1 [128][256] swizzled (overwrites x0) ----------
  {
    const float mu0 = smean[e0], rs0 = srstd[e0];
    const float mu1 = smean[e1], rs1 = srstd[e1];
    const int j0 = (q & 1) * 4;
#pragma unroll
    for (int msf = 0; msf < 4; ++msf) {
      const float4 gv = *(const float4*)(g1 + featBase + msf * 16 + q * 4);
      const float4 bev = *(const float4*)(be1 + featBase + msf * 16 + q * 4);
      const int g = wf * 8 + msf * 2 + (q >> 1);  // feat group 0..31
      const int gp = (g & 16) | ((g ^ c) & 15);
      f16x4 h0, h1;
#pragma unroll
      for (int r = 0; r < 4; ++r) {
        const float gr = COMP(gv, r), ber = COMP(bev, r);
        h0[r] = (f16_t)fmaxf((acc[msf][0][r] - mu0) * rs0 * gr + ber, 0.f);
        h1[r] = (f16_t)fmaxf((acc[msf][1][r] - mu1) * rs1 * gr + ber, 0.f);
      }
      *(f16x4*)(xlds + e0 * 256 + gp * 8 + j0) = h0;
      *(f16x4*)(xlds + e1 * 256 + gp * 8 + j0) = h1;
    }
  }
  __syncthreads();  // (4) x1 visible

  // ---------- GEMM2: K=256 in two k-halves; no barriers inside passes ----------
  f32x4 acc2[4][2];
#pragma unroll
  for (int msf = 0; msf < 4; ++msf)
#pragma unroll
    for (int n = 0; n < 2; ++n) acc2[msf][n] = (f32x4){0.f, 0.f, 0.f, 0.f};

#pragma unroll
  for (int kc = 0; kc < 4; ++kc) {  // pass 1: k = 0..127 (x1 groups 0..15)
    const int gp = ((kc * 4 + q) ^ c) & 15;
    f16x8 af[4], bf[2];
#pragma unroll
    for (int msf = 0; msf < 4; ++msf)
      af[msf] = *(const f16x8*)(wlds + (featBase + msf * 16 + c) * 128 + gp * 8);
    bf[0] = *(const f16x8*)(xlds + e0 * 256 + gp * 8);
    bf[1] = *(const f16x8*)(xlds + e1 * 256 + gp * 8);
#pragma unroll
    for (int msf = 0; msf < 4; ++msf)
#pragma unroll
      for (int n = 0; n < 2; ++n)
        acc2[msf][n] = __builtin_amdgcn_mfma_f32_16x16x32_f16(af[msf], bf[n], acc2[msf][n], 0, 0, 0);
  }
  __syncthreads();  // (5) W2h0 reads done
  stage64k(65536);  // W2 half1 -> wlds
  __syncthreads();  // (6) W2h1 drained

#pragma unroll
  for (int kc = 0; kc < 4; ++kc) {  // pass 2: k = 128..255 (x1 groups 16..31)
    const int gp = ((kc * 4 + q) ^ c) & 15;
    f16x8 af[4], bf[2];
#pragma unroll
    for (int msf = 0; msf < 4; ++msf)
      af[msf] = *(const f16x8*)(wlds + (featBase + msf * 16 + c) * 128 + gp * 8);
    bf[0] = *(const f16x8*)(xlds + e0 * 256 + 128 + gp * 8);
    bf[1] = *(const f16x8*)(xlds + e1 * 256 + 128 + gp * 8);
#pragma unroll
    for (int msf = 0; msf < 4; ++msf)
#pragma unroll
      for (int n = 0; n < 2; ++n)
        acc2[msf][n] = __builtin_amdgcn_mfma_f32_16x16x32_f16(af[msf], bf[n], acc2[msf][n], 0, 0, 0);
  }

  // ---------- LN2 stats ----------
  {
    float s0 = 0.f, s1 = 0.f, q0 = 0.f, q1 = 0.f;
#pragma unroll
    for (int msf = 0; msf < 4; ++msf) {
      const float4 bv = *(const float4*)(b2 + featBase + msf * 16 + q * 4);
#pragma unroll
      for (int r = 0; r < 4; ++r) {
        const float b = COMP(bv, r);
        float v0 = acc2[msf][0][r] + b, v1 = acc2[msf][1][r] + b;
        acc2[msf][0][r] = v0; acc2[msf][1][r] = v1;
        s0 += v0; q0 += v0 * v0;
        s1 += v1; q1 += v1 * v1;
      }
    }
    s0 += __shfl_xor(s0, 16, 64); s0 += __shfl_xor(s0, 32, 64);
    q0 += __shfl_xor(q0, 16, 64); q0 += __shfl_xor(q0, 32, 64);
    s1 += __shfl_xor(s1, 16, 64); s1 += __shfl_xor(s1, 32, 64);
    q1 += __shfl_xor(q1, 16, 64); q1 += __shfl_xor(q1, 32, 64);
    if (q == 0) {
      ssum[wf * 128 + e0] = s0; ssq[wf * 128 + e0] = q0;
      ssum[wf * 128 + e1] = s1; ssq[wf * 128 + e1] = q1;
    }
  }
  __syncthreads();  // (7)
  if (t < 128) {
    float s = ssum[t] + ssum[128 + t] + ssum[256 + t] + ssum[384 + t];
    float sq = ssq[t] + ssq[128 + t] + ssq[256 + t] + ssq[384 + t];
    float mu = s * (1.f / 256.f);
    float var = sq * (1.f / 256.f) - mu * mu;
    smean[t] = mu;
    srstd[t] = rsqrtf(var + 1e-5f);
  }
  __syncthreads();  // (8)

  // ---------- LN2 normalize + ReLU + dot(W3) + sigmoid ----------
  {
    const float mu0 = smean[e0], rs0 = srstd[e0];
    const float mu1 = smean[e1], rs1 = srstd[e1];
    float p0 = 0.f, p1 = 0.f;
#pragma unroll
    for (int msf = 0; msf < 4; ++msf) {
      const float4 gv = *(const float4*)(g2 + featBase + msf * 16 + q * 4);
      const float4 bev = *(const float4*)(be2 + featBase + msf * 16 + q * 4);
      const float4 wv = *(const float4*)(w3 + featBase + msf * 16 + q * 4);
#pragma unroll
      for (int r = 0; r < 4; ++r) {
        const float gr = COMP(gv, r), ber = COMP(bev, r), wr = COMP(wv, r);
        float v0 = fmaxf((acc2[msf][0][r] - mu0) * rs0 * gr + ber, 0.f);
        float v1 = fmaxf((acc2[msf][1][r] - mu1) * rs1 * gr + ber, 0.f);
        p0 = fmaf(v0, wr, p0);
        p1 = fmaf(v1, wr, p1);
      }
    }
    p0 += __shfl_xor(p0, 16, 64); p0 += __shfl_xor(p0, 32, 64);
    p1 += __shfl_xor(p1, 16, 64); p1 += __shfl_xor(p1, 32, 64);
    if (q == 0) {
      ssum[wf * 128 + e0] = p0;
      ssum[wf * 128 + e1] = p1;
    }
  }
  __syncthreads();  // (9)
  if (t < 128) {
    int e = ebase + t;
    if (e < E) {
      float sres = ssum[t] + ssum[128 + t] + ssum[256 + t] + ssum[384 + t] + b3[0];
      out[e] = 1.f / (1.f + __expf(-sres));
    }
  }
}

extern "C" void kernel_launch(void* const* d_in, const int* in_sizes, int n_in,
                              void* d_out, int out_size, void* d_ws, size_t ws_size,
                              hipStream_t stream) {
  const float* h = (const float*)d_in[0];
  const int* src = (const int*)d_in[1];
  const int* dst = (const int*)d_in[2];
  const float* W1 = (const float*)d_in[3];
  const float* b1 = (const float*)d_in[4];
  const float* g1 = (const float*)d_in[5];
  const float* be1 = (const float*)d_in[6];
  const float* W2 = (const float*)d_in[7];
  const float* b2 = (const float*)d_in[8];
  const float* g2 = (const float*)d_in[9];
  const float* be2 = (const float*)d_in[10];
  const float* W3 = (const float*)d_in[11];
  const float* b3 = (const float*)d_in[12];
  float* out = (float*)d_out;
  const int E = in_sizes[1];
  const int nrows = in_sizes[0] / 128;
  f16_t* wks = (f16_t*)d_ws;  // 98304 f16 = 196608 bytes

  wconv<<<256, 256, 0, stream>>>(W1, W2, wks);
  hipFuncSetAttribute((const void*)fused_mlp,
                      hipFuncAttributeMaxDynamicSharedMemorySize, LDS_BYTES);
  const int tiles = (E + 127) / 128;
  fused_mlp<<<tiles, 1024, LDS_BYTES, stream>>>(h, src, dst, wks, b1, g1, be1,
                                                b2, g2, be2, W3, b3, out, E, nrows);
}

// Round 8
// 297.019 us; speedup vs baseline: 2.4429x; 1.0922x over previous
//
#include <hip/hip_runtime.h>
#include <math.h>

typedef _Float16 f16_t;
typedef _Float16 f16x8 __attribute__((ext_vector_type(8)));
typedef _Float16 f16x4 __attribute__((ext_vector_type(4)));
typedef _Float16 f16x2 __attribute__((ext_vector_type(2)));
typedef __fp16 h16x2 __attribute__((ext_vector_type(2)));
typedef float f32x4 __attribute__((ext_vector_type(4)));

#define LDS_BYTES 68096

// fp32 -> fp16 weights into d_ws, k-chunk-major with 16B-group swizzle baked in.
// Chunk ck = [256 n][32 k] (8192 f16 = 16 KB). Element (n, k=ck*32+q*8+j) at
// chunkBase + n*32 + (q ^ ((n>>1)&3))*8 + j.  W1: chunks 0..3 at 0; W2: chunks 0..7 at 32768.
__global__ void wconv(const float* __restrict__ W1, const float* __restrict__ W2,
                      f16_t* __restrict__ o) {
  int i = blockIdx.x * 256 + threadIdx.x;  // 0..65535
  if (i < 32768) {
    int n = i >> 7, k = i & 127;
    int ck = k >> 5, q = (k >> 3) & 3, j = k & 7;
    o[ck * 8192 + n * 32 + (q ^ ((n >> 1) & 3)) * 8 + j] = (f16_t)W1[i];
  }
  {
    int n = i >> 8, k = i & 255;
    int ck = k >> 5, q = (k >> 3) & 3, j = k & 7;
    o[32768 + ck * 8192 + n * 32 + (q ^ ((n >> 1) & 3)) * 8 + j] = (f16_t)W2[i];
  }
}

__device__ __forceinline__ void stage16(const f16_t* g, f16_t* l) {
  __builtin_amdgcn_global_load_lds(
      (const __attribute__((address_space(1))) void*)g,
      (__attribute__((address_space(3))) void*)l, 16, 0, 0);
}

__device__ __forceinline__ f16x2 pk2(float a, float b) {
  union { h16x2 h; f16x2 f; } u;
  u.h = __builtin_amdgcn_cvt_pkrtz(a, b);
  return u.f;
}

#define COMP(v, r) ((r) == 0 ? (v).x : (r) == 1 ? (v).y : (r) == 2 ? (v).z : (v).w)

// Transposed fused MLP: D[feat][edge] = W @ x^T. Tile = 64 edges, 512 threads,
// 8 waves as 4 feat-rows (64 feats) x 2 edge-cols (32 edges). acc[4][2] = 32 regs
// (proven no-spill). Weights staged in 16 KB k-chunks through a 2x16KB ping-pong
// with ONE barrier per chunk (stage-next / compute-current / barrier).
// LDS 68096 B -> 2 blocks/CU: independent barrier domains hide phase stalls.
__global__ __launch_bounds__(512) void fused_mlp(
    const float* __restrict__ h,
    const int* __restrict__ src,
    const int* __restrict__ dst,
    const f16_t* __restrict__ wks,
    const float* __restrict__ b1, const float* __restrict__ g1, const float* __restrict__ be1,
    const float* __restrict__ b2, const float* __restrict__ g2, const float* __restrict__ be2,
    const float* __restrict__ w3, const float* __restrict__ b3,
    float* __restrict__ out, int E, int nrows) {
  extern __shared__ __attribute__((aligned(16))) char smem[];
  f16_t* wlds = (f16_t*)smem;               // 2 x 8192 f16 ping-pong (32 KB)
  f16_t* xbuf = (f16_t*)(smem + 32768);     // x0 [64][128]; later x1 [64][256] (32 KB)
  float* ssum = (float*)(smem + 65536);     // [4 wf][64 e]
  float* ssq  = (float*)(smem + 66560);     // [4 wf][64 e]
  float* smean = (float*)(smem + 67584);    // [64]
  float* srstd = (float*)(smem + 67840);    // [64]

  const int t = threadIdx.x;
  const int ebase = blockIdx.x * 64;

  auto stage_chunk = [&](int dbuf, int off) {  // 16 KB chunk, 512 thr x 16 B x 2
    const f16_t* g0 = wks + off + t * 8;
    f16_t* l0 = wlds + dbuf * 8192 + t * 8;
    stage16(g0, l0);
    stage16(g0 + 4096, l0 + 4096);
  };

  stage_chunk(0, 0);  // W1ck0 -> buf0, overlaps gather

  // ---------- gather: x0[m][k] = h[src][k]*h[dst][k], fp16, swizzled stride-128 ----------
  {
    const int m = t >> 3;   // edge 0..63
    const int j = t & 7;    // 16-float slice
    const int e = ebase + m;
    f16_t* xrow = xbuf + m * 128;
    const int g0 = ((j * 2) ^ m) & 15;
    const int g1i = ((j * 2 + 1) ^ m) & 15;
    if (e < E) {
      int si = src[e], di = dst[e];
      si = ((unsigned)si < (unsigned)nrows) ? si : 0;
      di = ((unsigned)di < (unsigned)nrows) ? di : 0;
      const float* hs = h + (long long)si * 128 + j * 16;
      const float* hd = h + (long long)di * 128 + j * 16;
      const float4 a0 = *(const float4*)(hs);
      const float4 a1 = *(const float4*)(hs + 4);
      const float4 a2 = *(const float4*)(hs + 8);
      const float4 a3 = *(const float4*)(hs + 12);
      const float4 c0 = *(const float4*)(hd);
      const float4 c1 = *(const float4*)(hd + 4);
      const float4 c2 = *(const float4*)(hd + 8);
      const float4 c3 = *(const float4*)(hd + 12);
      union { f16x8 v8; f16x2 v2[4]; } u0, u1;
      u0.v2[0] = pk2(a0.x * c0.x, a0.y * c0.y);
      u0.v2[1] = pk2(a0.z * c0.z, a0.w * c0.w);
      u0.v2[2] = pk2(a1.x * c1.x, a1.y * c1.y);
      u0.v2[3] = pk2(a1.z * c1.z, a1.w * c1.w);
      u1.v2[0] = pk2(a2.x * c2.x, a2.y * c2.y);
      u1.v2[1] = pk2(a2.z * c2.z, a2.w * c2.w);
      u1.v2[2] = pk2(a3.x * c3.x, a3.y * c3.y);
      u1.v2[3] = pk2(a3.z * c3.z, a3.w * c3.w);
      *(f16x8*)(xrow + g0 * 8) = u0.v8;
      *(f16x8*)(xrow + g1i * 8) = u1.v8;
    } else {
      f16x8 z = {};
      *(f16x8*)(xrow + g0 * 8) = z;
      *(f16x8*)(xrow + g1i * 8) = z;
    }
  }
  __syncthreads();  // b1: x0 + W1ck0 ready

  const int lane = t & 63;
  const int wave = t >> 6;
  const int wf = wave >> 1;  // 0..3: 64 feats
  const int we = wave & 1;   // 0..1: 32 edges
  const int c = lane & 15;
  const int q = lane >> 4;
  const int qp = q ^ ((c >> 1) & 3);  // weight-chunk swizzle (per-lane const)
  const int featBase = wf * 64;
  const int e0 = we * 32 + c, e1 = e0 + 16;
  const int woff = (featBase + c) * 32 + qp * 8;  // + msf*512, + buf*8192

  // ---------- GEMM1: K=128, 4 chunks, 1 barrier each ----------
  f32x4 acc[4][2];
#pragma unroll
  for (int msf = 0; msf < 4; ++msf)
#pragma unroll
    for (int n = 0; n < 2; ++n) acc[msf][n] = (f32x4){0.f, 0.f, 0.f, 0.f};

#pragma unroll
  for (int kc = 0; kc < 4; ++kc) {
    if (kc < 3) stage_chunk((kc + 1) & 1, (kc + 1) * 8192);  // W1ck(kc+1)
    else        stage_chunk(0, 32768);                        // W2ck0 (buf0 free since kc2)
    const int rb = (kc & 1) * 8192;
    const int gp = ((kc * 4 + q) ^ c) & 15;
    f16x8 af[4], bf[2];
#pragma unroll
    for (int msf = 0; msf < 4; ++msf)
      af[msf] = *(const f16x8*)(wlds + rb + woff + msf * 512);
    bf[0] = *(const f16x8*)(xbuf + e0 * 128 + gp * 8);
    bf[1] = *(const f16x8*)(xbuf + e1 * 128 + gp * 8);
#pragma unroll
    for (int msf = 0; msf < 4; ++msf)
#pragma unroll
      for (int n = 0; n < 2; ++n)
        acc[msf][n] = __builtin_amdgcn_mfma_f32_16x16x32_f16(af[msf], bf[n], acc[msf][n], 0, 0, 0);
    if (kc < 3) __syncthreads();  // b2..b4
  }

  // ---------- LN1 stats (dedicated region; concurrent with other waves' kc3) ----------
  {
    float s0 = 0.f, s1 = 0.f, q0 = 0.f, q1 = 0.f;
#pragma unroll
    for (int msf = 0; msf < 4; ++msf) {
      const float4 bv = *(const float4*)(b1 + featBase + msf * 16 + q * 4);
#pragma unroll
      for (int r = 0; r < 4; ++r) {
        const float b = COMP(bv, r);
        float v0 = acc[msf][0][r] + b, v1 = acc[msf][1][r] + b;
        acc[msf][0][r] = v0; acc[msf][1][r] = v1;
        s0 += v0; q0 += v0 * v0;
        s1 += v1; q1 += v1 * v1;
      }
    }
    s0 += __shfl_xor(s0, 16, 64); s0 += __shfl_xor(s0, 32, 64);
    q0 += __shfl_xor(q0, 16, 64); q0 += __shfl_xor(q0, 32, 64);
    s1 += __shfl_xor(s1, 16, 64); s1 += __shfl_xor(s1, 32, 64);
    q1 += __shfl_xor(q1, 16, 64); q1 += __shfl_xor(q1, 32, 64);
    if (q == 0) {
      ssum[wf * 64 + e0] = s0; ssq[wf * 64 + e0] = q0;
      ssum[wf * 64 + e1] = s1; ssq[wf * 64 + e1] = q1;
    }
  }
  __syncthreads();  // b5: stats ready; W2ck0 drained; all GEMM1 reads done
  stage_chunk(1, 32768 + 8192);  // W2ck1 -> buf1 (free since b5), drains at b6
  if (t < 64) {
    float s = ssum[t] + ssum[64 + t] + ssum[128 + t] + ssum[192 + t];
    float sq = ssq[t] + ssq[64 + t] + ssq[128 + t] + ssq[192 + t];
    float mu = s * (1.f / 256.f);
    float var = sq * (1.f / 256.f) - mu * mu;
    smean[t] = mu;
    srstd[t] = rsqrtf(var + 1e-5f);
  }
  __syncthreads();  // b6: mean/rstd ready; W2ck1 drained

  // ---------- LN1 normalize + ReLU -> x1 [64][256] (overwrites x0; x0 dead) ----------
  {
    const float mu0 = smean[e0], rs0 = srstd[e0];
    const float mu1 = smean[e1], rs1 = srstd[e1];
    const int j0 = (q & 1) * 4;
#pragma unroll
    for (int msf = 0; msf < 4; ++msf) {
      const float4 gv = *(const float4*)(g1 + featBase + msf * 16 + q * 4);
      const float4 bev = *(const float4*)(be1 + featBase + msf * 16 + q * 4);
      const int g = wf * 8 + msf * 2 + (q >> 1);  // feat 16B-group 0..31
      float v00, v01, v02, v03, v10, v11, v12, v13;
      v00 = fmaxf((acc[msf][0][0] - mu0) * rs0 * gv.x + bev.x, 0.f);
      v01 = fmaxf((acc[msf][0][1] - mu0) * rs0 * gv.y + bev.y, 0.f);
      v02 = fmaxf((acc[msf][0][2] - mu0) * rs0 * gv.z + bev.z, 0.f);
      v03 = fmaxf((acc[msf][0][3] - mu0) * rs0 * gv.w + bev.w, 0.f);
      v10 = fmaxf((acc[msf][1][0] - mu1) * rs1 * gv.x + bev.x, 0.f);
      v11 = fmaxf((acc[msf][1][1] - mu1) * rs1 * gv.y + bev.y, 0.f);
      v12 = fmaxf((acc[msf][1][2] - mu1) * rs1 * gv.z + bev.z, 0.f);
      v13 = fmaxf((acc[msf][1][3] - mu1) * rs1 * gv.w + bev.w, 0.f);
      union { f16x4 v4; f16x2 v2[2]; } h0, h1;
      h0.v2[0] = pk2(v00, v01); h0.v2[1] = pk2(v02, v03);
      h1.v2[0] = pk2(v10, v11); h1.v2[1] = pk2(v12, v13);
      const int gp0 = (g & 16) | ((g ^ e0) & 15);
      const int gp1 = (g & 16) | ((g ^ e1) & 15);
      *(f16x4*)(xbuf + e0 * 256 + gp0 * 8 + j0) = h0.v4;
      *(f16x4*)(xbuf + e1 * 256 + gp1 * 8 + j0) = h1.v4;
    }
  }
  __syncthreads();  // b7: x1 visible

  // ---------- GEMM2: K=256, 8 chunks (ck0,ck1 pre-staged), 1 barrier each ----------
  f32x4 acc2[4][2];
#pragma unroll
  for (int msf = 0; msf < 4; ++msf)
#pragma unroll
    for (int n = 0; n < 2; ++n) acc2[msf][n] = (f32x4){0.f, 0.f, 0.f, 0.f};

#pragma unroll
  for (int kc = 0; kc < 8; ++kc) {
    if (kc >= 1 && kc <= 6)
      stage_chunk((kc + 1) & 1, 32768 + (kc + 1) * 8192);  // W2ck(kc+1)
    const int rb = (kc & 1) * 8192;
    const int g = kc * 4 + q;  // 0..31
    const int gp0 = (g & 16) | ((g ^ e0) & 15);
    const int gp1 = (g & 16) | ((g ^ e1) & 15);
    f16x8 af[4], bf[2];
#pragma unroll
    for (int msf = 0; msf < 4; ++msf)
      af[msf] = *(const f16x8*)(wlds + rb + woff + msf * 512);
    bf[0] = *(const f16x8*)(xbuf + e0 * 256 + gp0 * 8);
    bf[1] = *(const f16x8*)(xbuf + e1 * 256 + gp1 * 8);
#pragma unroll
    for (int msf = 0; msf < 4; ++msf)
#pragma unroll
      for (int n = 0; n < 2; ++n)
        acc2[msf][n] = __builtin_amdgcn_mfma_f32_16x16x32_f16(af[msf], bf[n], acc2[msf][n], 0, 0, 0);
    if (kc < 7) __syncthreads();  // b8..b14
  }

  // ---------- LN2 stats ----------
  {
    float s0 = 0.f, s1 = 0.f, q0 = 0.f, q1 = 0.f;
#pragma unroll
    for (int msf = 0; msf < 4; ++msf) {
      const float4 bv = *(const float4*)(b2 + featBase + msf * 16 + q * 4);
#pragma unroll
      for (int r = 0; r < 4; ++r) {
        const float b = COMP(bv, r);
        float v0 = acc2[msf][0][r] + b, v1 = acc2[msf][1][r] + b;
        acc2[msf][0][r] = v0; acc2[msf][1][r] = v1;
        s0 += v0; q0 += v0 * v0;
        s1 += v1; q1 += v1 * v1;
      }
    }
    s0 += __shfl_xor(s0, 16, 64); s0 += __shfl_xor(s0, 32, 64);
    q0 += __shfl_xor(q0, 16, 64); q0 += __shfl_xor(q0, 32, 64);
    s1 += __shfl_xor(s1, 16, 64); s1 += __shfl_xor(s1, 32, 64);
    q1 += __shfl_xor(q1, 16, 64); q1 += __shfl_xor(q1, 32, 64);
    if (q == 0) {
      ssum[wf * 64 + e0] = s0; ssq[wf * 64 + e0] = q0;
      ssum[wf * 64 + e1] = s1; ssq[wf * 64 + e1] = q1;
    }
  }
  __syncthreads();  // b15
  if (t < 64) {
    float s = ssum[t] + ssum[64 + t] + ssum[128 + t] + ssum[192 + t];
    float sq = ssq[t] + ssq[64 + t] + ssq[128 + t] + ssq[192 + t];
    float mu = s * (1.f / 256.f);
    float var = sq * (1.f / 256.f) - mu * mu;
    smean[t] = mu;
    srstd[t] = rsqrtf(var + 1e-5f);
  }
  __syncthreads();  // b16

  // ---------- LN2 normalize + ReLU + dot(W3) + sigmoid ----------
  {
    const float mu0 = smean[e0], rs0 = srstd[e0];
    const float mu1 = smean[e1], rs1 = srstd[e1];
    float p0 = 0.f, p1 = 0.f;
#pragma unroll
    for (int msf = 0; msf < 4; ++msf) {
      const float4 gv = *(const float4*)(g2 + featBase + msf * 16 + q * 4);
      const float4 bev = *(const float4*)(be2 + featBase + msf * 16 + q * 4);
      const float4 wv = *(const float4*)(w3 + featBase + msf * 16 + q * 4);
#pragma unroll
      for (int r = 0; r < 4; ++r) {
        const float gr = COMP(gv, r), ber = COMP(bev, r), wr = COMP(wv, r);
        float v0 = fmaxf((acc2[msf][0][r] - mu0) * rs0 * gr + ber, 0.f);
        float v1 = fmaxf((acc2[msf][1][r] - mu1) * rs1 * gr + ber, 0.f);
        p0 = fmaf(v0, wr, p0);
        p1 = fmaf(v1, wr, p1);
      }
    }
    p0 += __shfl_xor(p0, 16, 64); p0 += __shfl_xor(p0, 32, 64);
    p1 += __shfl_xor(p1, 16, 64); p1 += __shfl_xor(p1, 32, 64);
    if (q == 0) {
      ssum[wf * 64 + e0] = p0;  // old ssum dead after b16 reduce
      ssum[wf * 64 + e1] = p1;
    }
  }
  __syncthreads();  // b17
  if (t < 64) {
    int e = ebase + t;
    if (e < E) {
      float sres = ssum[t] + ssum[64 + t] + ssum[128 + t] + ssum[192 + t] + b3[0];
      out[e] = 1.f / (1.f + __expf(-sres));
    }
  }
}

extern "C" void kernel_launch(void* const* d_in, const int* in_sizes, int n_in,
                              void* d_out, int out_size, void* d_ws, size_t ws_size,
                              hipStream_t stream) {
  const float* h = (const float*)d_in[0];
  const int* src = (const int*)d_in[1];
  const int* dst = (const int*)d_in[2];
  const float* W1 = (const float*)d_in[3];
  const float* b1 = (const float*)d_in[4];
  const float* g1 = (const float*)d_in[5];
  const float* be1 = (const float*)d_in[6];
  const float* W2 = (const float*)d_in[7];
  const float* b2 = (const float*)d_in[8];
  const float* g2 = (const float*)d_in[9];
  const float* be2 = (const float*)d_in[10];
  const float* W3 = (const float*)d_in[11];
  const float* b3 = (const float*)d_in[12];
  float* out = (float*)d_out;
  const int E = in_sizes[1];
  const int nrows = in_sizes[0] / 128;
  f16_t* wks = (f16_t*)d_ws;  // 98304 f16 = 196608 bytes

  wconv<<<256, 256, 0, stream>>>(W1, W2, wks);
  (void)hipFuncSetAttribute((const void*)fused_mlp,
                            hipFuncAttributeMaxDynamicSharedMemorySize, LDS_BYTES);
  const int tiles = (E + 63) / 64;
  fused_mlp<<<tiles, 512, LDS_BYTES, stream>>>(h, src, dst, wks, b1, g1, be1,
                                               b2, g2, be2, W3, b3, out, E, nrows);
}